// Round 18
// baseline (301.073 us; speedup 1.0000x reference)
//
#include <hip/hip_runtime.h>
#include <math.h>

// ---------------------------------------------------------------------------
// SimGNN forward on MI355X — R29 best (299.7 us) + small-kernel elimination
// (R30; 3rd submission after broker timeout + container failure).
// INFRA NOTE: R30 has failed twice to run (timeout R16-round, container-fail
// R17-round). Kernel re-audited: uniform barriers, bounds-guarded, 7.2 KB
// LDS — no fault path found. If container fails a 3rd time, next round
// reverts to R29-exact to disambiguate kernel-vs-infra.
// R29 WIN: NSLICE 64->256 (fillC full-chip), 312.7 -> 299.7.
// R30: (a) scale0 fused into fillC phase 4 — slice block already owns its
// nodes' dinv (stashed in LDS at phase 2); streams f32->scale->f16 for its
// 512 nodes. (b) packW fused into bucket_fused tail (blocks 0..39, one
// element/thread). Kills 2 launches + gaps; math bit-identical.
// R28 WIN: single-pass bucket + pool2 parity. R27 WIN: agg64+GEMM fusion.
// R25: gathers L2 request-rate bound (R20/R24/R25) — structure frozen at
// ~49 us/pass x 3. R23 WIN: packed-bkt. R22 WIN: agg64 parity. R20: HG=512
// SETTLED. R17 WIN: agg32 parity. R26: last-block-flag banned.
// Pipeline: bucket_fused(+packW) -> fillC_fused(+scale0)
//   -> agg_gemm1 -> agg_gemm2 -> agg32_colsum -> pool2 -> ntn
// ---------------------------------------------------------------------------

#define NSLICE 256
#define NBLK   256
#define FILLC_T 512

typedef _Float16 f16x8 __attribute__((ext_vector_type(8)));
typedef _Float16 f16x4 __attribute__((ext_vector_type(4)));
typedef _Float16 f16x2 __attribute__((ext_vector_type(2)));
typedef float    f32x4 __attribute__((ext_vector_type(4)));

// ---- R28/R29/R30: single-pass bucket build + packW tail.
__global__ void bucket_fused_kernel(const int* __restrict__ ei1, const int* __restrict__ ei2,
                                    int E, int N, int* __restrict__ gslice,
                                    unsigned* __restrict__ bkt, int chunk, int nsb, int cap,
                                    const float* __restrict__ W1, const float* __restrict__ W2,
                                    const float* __restrict__ W3, _Float16* __restrict__ pk) {
    __shared__ int cnt[NSLICE];
    __shared__ int rbase[NSLICE];
    int t = threadIdx.x;                   // blockDim.x == 256 == NSLICE
    if (t < NSLICE) cnt[t] = 0;
    __syncthreads();
    int E2 = 2 * E;
    int lo = blockIdx.x * chunk;
    int hi = lo + chunk; if (hi > E2) hi = E2;
    for (int i = lo + t; i < hi; i += blockDim.x) {
        int dst = (i < E) ? ei1[E + i] : (ei2[E + (i - E)] + N);
        atomicAdd(&cnt[dst >> nsb], 1);
    }
    __syncthreads();
    if (t < NSLICE) {
        int c = cnt[t];
        rbase[t] = c ? atomicAdd(&gslice[t], c) : 0;
        cnt[t] = 0;                        // reuse as intra-block cursor
    }
    __syncthreads();
    unsigned mask = (1u << nsb) - 1u;
    for (int i = lo + t; i < hi; i += blockDim.x) {
        int src, dst;
        if (i < E) { src = ei1[i];         dst = ei1[E + i]; }
        else       { src = ei2[i - E] + N; dst = ei2[E + (i - E)] + N; }
        int s = dst >> nsb;
        int p = rbase[s] + atomicAdd(&cnt[s], 1);
        if (p >= cap) p = cap - 1;         // overflow clamp (no fault)
        bkt[(size_t)s * cap + p] = ((unsigned)src << nsb) | ((unsigned)dst & mask);
    }
    // R30: packW tail (blocks 0..39 cover 10240 elements)
    if (blockIdx.x < 40) {
        int tt = blockIdx.x * 256 + t;
        if (tt < 8192) {
            const float* W = (tt < 4096) ? W1 : W2;
            int idx = tt & 4095;
            int j = idx & 7, slot = idx >> 3;
            int lane = slot & 63, s2 = (slot >> 6) & 1, ct = slot >> 7;
            int k = s2 * 32 + ((lane >> 4) << 3) + j;
            int n = ct * 16 + (lane & 15);
            pk[tt] = (_Float16)W[k * 64 + n];
        } else if (tt < 10240) {
            int idx = tt - 8192;
            int j = idx & 7, slot = idx >> 3;
            int lane = slot & 63, s2 = (slot >> 6) & 1, ct = slot >> 7;
            int k = s2 * 32 + ((lane >> 4) << 3) + j;
            int n = ct * 16 + (lane & 15);
            pk[tt] = (_Float16)W3[k * 32 + n];
        }
    }
}

// ---- fillC_fused (R29/R30): 256 blocks x 512 threads. Phase 1 histogram ->
// phase 2 scan (row_ptr/dinv; dinv stashed in LDS) -> phase 3 col placement
// -> phase 4 (R30) scale this slice's node features f32->f16 (was scale0).
__global__ void fillC_fused_kernel(const unsigned* __restrict__ bkt,
                                   const int* __restrict__ gslice,
                                   int* __restrict__ row_ptr, float* __restrict__ dinv,
                                   int* __restrict__ col,
                                   const float* __restrict__ f1, const float* __restrict__ f2,
                                   _Float16* __restrict__ xs,
                                   int M, int Nn, int nsb, int cap) {
    extern __shared__ int sm[];           // [nbins] hist/cursor + [512] scan + [nbins] dinv
    int nbins = 1 << nsb;
    unsigned mask = (unsigned)nbins - 1u;
    int* hist = sm;
    int* ssum = sm + nbins;
    float* sdinv = (float*)(sm + nbins + FILLC_T);
    __shared__ int gs[NSLICE];
    int slice = blockIdx.x;
    int lo = slice << nsb;
    int t = threadIdx.x;                  // blockDim.x == FILLC_T
    for (int j = t; j < NSLICE; j += FILLC_T) gs[j] = gslice[j];
    for (int j = t; j < nbins; j += FILLC_T) hist[j] = 0;
    __syncthreads();
    int sstart = 0;
    for (int k = 0; k < slice; ++k) sstart += gs[k];
    int scount = gs[slice];
    size_t sb = (size_t)slice * cap;
    // Phase 1: histogram over low bits
    for (int i = t; i < scount; i += FILLC_T)
        atomicAdd(&hist[bkt[sb + i] & mask], 1);
    __syncthreads();
    // Phase 2: exclusive scan over nbins
    const int PER = nbins >> 9;           // nbins/512
    int base = t * PER;
    int vals[8];                          // supports nsb up to 12
    int acc = 0;
    for (int k = 0; k < PER; ++k) { vals[k] = hist[base + k]; acc += vals[k]; }
    ssum[t] = acc;
    __syncthreads();
    for (int off = 1; off < FILLC_T; off <<= 1) {
        int v = (t >= off) ? ssum[t - off] : 0;
        __syncthreads();
        ssum[t] += v;
        __syncthreads();
    }
    int run = sstart + ((t == 0) ? 0 : ssum[t - 1]);
    for (int k = 0; k < PER; ++k) {
        int idx = lo + base + k;
        float dv = rsqrtf((float)(vals[k] + 1));
        if (idx < M) {
            row_ptr[idx] = run;
            dinv[idx] = dv;
        }
        sdinv[base + k] = dv;
        hist[base + k] = run;             // becomes the global write cursor
        run += vals[k];
    }
    __syncthreads();
    if (slice == NSLICE - 1 && t == 0) row_ptr[M] = sstart + scount;  // = E2
    // Phase 3: place edges (src = high bits)
    for (int i = t; i < scount; i += FILLC_T) {
        unsigned w = bkt[sb + i];
        int p = atomicAdd(&hist[w & mask], 1);
        col[p] = (int)(w >> nsb);
    }
    // Phase 4 (R30): scale this slice's node features (was scale0_kernel).
    for (int j = t; j < (nbins << 4); j += FILLC_T) {
        int n = j >> 4, part = j & 15;
        int idx = lo + n;
        if (idx < M) {
            const float* srcp = (idx < Nn) ? (f1 + (size_t)idx * 64 + part * 4)
                                           : (f2 + (size_t)(idx - Nn) * 64 + part * 4);
            float dv = sdinv[n];
            float4 v = *(const float4*)srcp;
            f16x4 o = { (_Float16)(v.x * dv), (_Float16)(v.y * dv),
                        (_Float16)(v.z * dv), (_Float16)(v.w * dv) };
            *(f16x4*)(xs + (size_t)idx * 64 + part * 4) = o;
        }
    }
}

// Gather one node's 64-f16 row (f16x4 lane slice), R25-exact loop.
__device__ inline void gather_row4(const _Float16* __restrict__ xs,
                                   const int* __restrict__ row_ptr,
                                   const int* __restrict__ col,
                                   int v, int l, float a[4]) {
    const f16x4* row = (const f16x4*)(xs + (size_t)v * 64);
    f16x4 sv = row[l];
    a[0] = (float)sv[0]; a[1] = (float)sv[1]; a[2] = (float)sv[2]; a[3] = (float)sv[3];
    int s = row_ptr[v], e = row_ptr[v + 1];
    int i = s;
    for (; i + 8 <= e; i += 8) {
        int u0 = col[i],     u1 = col[i + 1], u2 = col[i + 2], u3 = col[i + 3];
        int u4 = col[i + 4], u5 = col[i + 5], u6 = col[i + 6], u7 = col[i + 7];
        f16x4 p0 = ((const f16x4*)(xs + (size_t)u0 * 64))[l];
        f16x4 p1 = ((const f16x4*)(xs + (size_t)u1 * 64))[l];
        f16x4 p2 = ((const f16x4*)(xs + (size_t)u2 * 64))[l];
        f16x4 p3 = ((const f16x4*)(xs + (size_t)u3 * 64))[l];
        f16x4 p4 = ((const f16x4*)(xs + (size_t)u4 * 64))[l];
        f16x4 p5 = ((const f16x4*)(xs + (size_t)u5 * 64))[l];
        f16x4 p6 = ((const f16x4*)(xs + (size_t)u6 * 64))[l];
        f16x4 p7 = ((const f16x4*)(xs + (size_t)u7 * 64))[l];
        a[0] += (((float)p0[0] + (float)p1[0]) + ((float)p2[0] + (float)p3[0]))
              + (((float)p4[0] + (float)p5[0]) + ((float)p6[0] + (float)p7[0]));
        a[1] += (((float)p0[1] + (float)p1[1]) + ((float)p2[1] + (float)p3[1]))
              + (((float)p4[1] + (float)p5[1]) + ((float)p6[1] + (float)p7[1]));
        a[2] += (((float)p0[2] + (float)p1[2]) + ((float)p2[2] + (float)p3[2]))
              + (((float)p4[2] + (float)p5[2]) + ((float)p6[2] + (float)p7[2]));
        a[3] += (((float)p0[3] + (float)p1[3]) + ((float)p2[3] + (float)p3[3]))
              + (((float)p4[3] + (float)p5[3]) + ((float)p6[3] + (float)p7[3]));
    }
    for (; i + 4 <= e; i += 4) {
        int u0 = col[i], u1 = col[i + 1], u2 = col[i + 2], u3 = col[i + 3];
        f16x4 p0 = ((const f16x4*)(xs + (size_t)u0 * 64))[l];
        f16x4 p1 = ((const f16x4*)(xs + (size_t)u1 * 64))[l];
        f16x4 p2 = ((const f16x4*)(xs + (size_t)u2 * 64))[l];
        f16x4 p3 = ((const f16x4*)(xs + (size_t)u3 * 64))[l];
        a[0] += ((float)p0[0] + (float)p1[0]) + ((float)p2[0] + (float)p3[0]);
        a[1] += ((float)p0[1] + (float)p1[1]) + ((float)p2[1] + (float)p3[1]);
        a[2] += ((float)p0[2] + (float)p1[2]) + ((float)p2[2] + (float)p3[2]);
        a[3] += ((float)p0[3] + (float)p1[3]) + ((float)p2[3] + (float)p3[3]);
    }
    for (; i < e; ++i) {
        f16x4 p = ((const f16x4*)(xs + (size_t)col[i] * 64))[l];
        a[0] += (float)p[0]; a[1] += (float)p[1]; a[2] += (float)p[2]; a[3] += (float)p[3];
    }
}

// R27: fused agg64 + GEMM1. Block = 16 quarter-waves = 16 nodes = one MFMA
// tile. Gather -> LDS[16][72] -> 4 waves x 1 ct-tile. g=bid&1 parity kept.
__global__ void agg_gemm1_kernel(const _Float16* __restrict__ xs, _Float16* __restrict__ out,
                                 const int* __restrict__ row_ptr, const int* __restrict__ col,
                                 const _Float16* __restrict__ pk, const float* __restrict__ b1,
                                 const float* __restrict__ dinv, int N) {
    __shared__ _Float16 xl[16][72];
    int g = blockIdx.x & 1;
    int tile = blockIdx.x >> 1;
    int t = threadIdx.x;
    int qw = t >> 4, l = t & 15;
    int nv = tile * 16 + qw;
    int v0 = g * N + tile * 16;
    if (nv < N) {
        int v = g * N + nv;
        float a[4];
        gather_row4(xs, row_ptr, col, v, l, a);
        float dvv = dinv[v];
        f16x4 o = { (_Float16)(a[0] * dvv), (_Float16)(a[1] * dvv),
                    (_Float16)(a[2] * dvv), (_Float16)(a[3] * dvv) };
        *(f16x4*)&xl[qw][l * 4] = o;
    } else {
        f16x4 z = { (_Float16)0.f, (_Float16)0.f, (_Float16)0.f, (_Float16)0.f };
        *(f16x4*)&xl[qw][l * 4] = z;
    }
    __syncthreads();
    int ct = t >> 6;                       // wave id = column tile
    int lane = t & 63;
    int l15 = lane & 15, q = lane >> 4;
    const f16x8* arow = (const f16x8*)&xl[l15][0];
    f16x8 a0 = arow[q];
    f16x8 a1 = arow[q + 4];
    const f16x8* bp = (const f16x8*)pk;
    f32x4 c = {0.f, 0.f, 0.f, 0.f};
    c = __builtin_amdgcn_mfma_f32_16x16x32_f16(a0, bp[(ct * 2 + 0) * 64 + lane], c, 0, 0, 0);
    c = __builtin_amdgcn_mfma_f32_16x16x32_f16(a1, bp[(ct * 2 + 1) * 64 + lane], c, 0, 0, 0);
    float bj = b1[ct * 16 + l15];
    #pragma unroll
    for (int r = 0; r < 4; ++r) {
        int nr = tile * 16 + q * 4 + r;
        if (nr < N) {
            int vr = v0 + q * 4 + r;
            out[(size_t)vr * 64 + ct * 16 + l15] =
                (_Float16)(fmaxf(c[r] + bj, 0.f) * dinv[vr]);
        }
    }
}

// R27: fused agg64 + GEMM2+GEMM3. Gather -> LDS -> relu(t@W2+b2) -> LDS2
// -> (@W3)*dinv -> h3s.
__global__ void agg_gemm2_kernel(const _Float16* __restrict__ xs, _Float16* __restrict__ out,
                                 const int* __restrict__ row_ptr, const int* __restrict__ col,
                                 const _Float16* __restrict__ pk2, const _Float16* __restrict__ pk3,
                                 const float* __restrict__ b2, const float* __restrict__ dinv,
                                 int N) {
    __shared__ _Float16 xl[16][72];
    __shared__ _Float16 x2[16][72];
    int g = blockIdx.x & 1;
    int tile = blockIdx.x >> 1;
    int t = threadIdx.x;
    int qw = t >> 4, l = t & 15;
    int nv = tile * 16 + qw;
    int v0 = g * N + tile * 16;
    if (nv < N) {
        int v = g * N + nv;
        float a[4];
        gather_row4(xs, row_ptr, col, v, l, a);
        float dvv = dinv[v];
        f16x4 o = { (_Float16)(a[0] * dvv), (_Float16)(a[1] * dvv),
                    (_Float16)(a[2] * dvv), (_Float16)(a[3] * dvv) };
        *(f16x4*)&xl[qw][l * 4] = o;
    } else {
        f16x4 z = { (_Float16)0.f, (_Float16)0.f, (_Float16)0.f, (_Float16)0.f };
        *(f16x4*)&xl[qw][l * 4] = z;
    }
    __syncthreads();
    int ct = t >> 6;
    int lane = t & 63;
    int l15 = lane & 15, q = lane >> 4;
    {
        const f16x8* arow = (const f16x8*)&xl[l15][0];
        f16x8 a0 = arow[q];
        f16x8 a1 = arow[q + 4];
        const f16x8* bp2 = (const f16x8*)pk2;
        f32x4 c = {0.f, 0.f, 0.f, 0.f};
        c = __builtin_amdgcn_mfma_f32_16x16x32_f16(a0, bp2[(ct * 2 + 0) * 64 + lane], c, 0, 0, 0);
        c = __builtin_amdgcn_mfma_f32_16x16x32_f16(a1, bp2[(ct * 2 + 1) * 64 + lane], c, 0, 0, 0);
        float bj = b2[ct * 16 + l15];
        #pragma unroll
        for (int r = 0; r < 4; ++r)
            x2[q * 4 + r][ct * 16 + l15] = (_Float16)fmaxf(c[r] + bj, 0.f);
    }
    __syncthreads();
    if (ct < 2) {
        const f16x8* er = (const f16x8*)&x2[l15][0];
        f16x8 e0 = er[q];
        f16x8 e1 = er[q + 4];
        const f16x8* bp3 = (const f16x8*)pk3;
        f32x4 c = {0.f, 0.f, 0.f, 0.f};
        c = __builtin_amdgcn_mfma_f32_16x16x32_f16(e0, bp3[(ct * 2 + 0) * 64 + lane], c, 0, 0, 0);
        c = __builtin_amdgcn_mfma_f32_16x16x32_f16(e1, bp3[(ct * 2 + 1) * 64 + lane], c, 0, 0, 0);
        #pragma unroll
        for (int r = 0; r < 4; ++r) {
            int nr = tile * 16 + q * 4 + r;
            if (nr < N) {
                int vr = v0 + q * 4 + r;
                out[(size_t)vr * 32 + ct * 16 + l15] = (_Float16)(c[r] * dinv[vr]);
            }
        }
    }
}

// agg32: quarter-wave per node; a3 f32 out; fused colsums.
// R17 parity split; HG=512 SETTLED (R14+R20: L2 queue-bound).
__global__ void agg32_colsum_kernel(const _Float16* __restrict__ hs, float* __restrict__ out,
                                    const int* __restrict__ row_ptr, const int* __restrict__ col,
                                    const float* __restrict__ dinv, const float* __restrict__ b,
                                    float* __restrict__ msum, int N, int halfgrid) {
    int g = blockIdx.x & 1;
    int bid = blockIdx.x >> 1;
    int t = threadIdx.x;
    int l = t & 15;
    int qw = (bid * blockDim.x + t) >> 4;
    int nqw = (halfgrid * blockDim.x) >> 4;
    float blx = b[2 * l], bly = b[2 * l + 1];
    float csx = 0.f, csy = 0.f;
    int base = g * N;
    for (int vv = qw; vv < N; vv += nqw) {
        int v = base + vv;
        f16x2 sv = ((const f16x2*)(hs + (size_t)v * 32))[l];
        float ax = (float)sv.x, ay = (float)sv.y;
        int s = row_ptr[v], e = row_ptr[v + 1];
        int i = s;
        for (; i + 8 <= e; i += 8) {
            int u0 = col[i],     u1 = col[i + 1], u2 = col[i + 2], u3 = col[i + 3];
            int u4 = col[i + 4], u5 = col[i + 5], u6 = col[i + 6], u7 = col[i + 7];
            f16x2 p0 = ((const f16x2*)(hs + (size_t)u0 * 32))[l];
            f16x2 p1 = ((const f16x2*)(hs + (size_t)u1 * 32))[l];
            f16x2 p2 = ((const f16x2*)(hs + (size_t)u2 * 32))[l];
            f16x2 p3 = ((const f16x2*)(hs + (size_t)u3 * 32))[l];
            f16x2 p4 = ((const f16x2*)(hs + (size_t)u4 * 32))[l];
            f16x2 p5 = ((const f16x2*)(hs + (size_t)u5 * 32))[l];
            f16x2 p6 = ((const f16x2*)(hs + (size_t)u6 * 32))[l];
            f16x2 p7 = ((const f16x2*)(hs + (size_t)u7 * 32))[l];
            ax += (((float)p0.x + (float)p1.x) + ((float)p2.x + (float)p3.x))
                + (((float)p4.x + (float)p5.x) + ((float)p6.x + (float)p7.x));
            ay += (((float)p0.y + (float)p1.y) + ((float)p2.y + (float)p3.y))
                + (((float)p4.y + (float)p5.y) + ((float)p6.y + (float)p7.y));
        }
        for (; i + 4 <= e; i += 4) {
            int u0 = col[i], u1 = col[i + 1], u2 = col[i + 2], u3 = col[i + 3];
            f16x2 p0 = ((const f16x2*)(hs + (size_t)u0 * 32))[l];
            f16x2 p1 = ((const f16x2*)(hs + (size_t)u1 * 32))[l];
            f16x2 p2 = ((const f16x2*)(hs + (size_t)u2 * 32))[l];
            f16x2 p3 = ((const f16x2*)(hs + (size_t)u3 * 32))[l];
            ax += ((float)p0.x + (float)p1.x) + ((float)p2.x + (float)p3.x);
            ay += ((float)p0.y + (float)p1.y) + ((float)p2.y + (float)p3.y);
        }
        for (; i < e; ++i) {
            f16x2 p = ((const f16x2*)(hs + (size_t)col[i] * 32))[l];
            ax += (float)p.x; ay += (float)p.y;
        }
        float dv = dinv[v];
        float ox = ax * dv + blx, oy = ay * dv + bly;
        *(float2*)(out + (size_t)v * 32 + 2 * l) = make_float2(ox, oy);
        csx += ox; csy += oy;
    }
    __shared__ float spx[256], spy[256];
    spx[t] = csx; spy[t] = csy;
    __syncthreads();
    if (t < 16) {
        float sx = 0.f, sy = 0.f;
        for (int w = 0; w < 16; ++w) { sx += spx[w * 16 + t]; sy += spy[w * 16 + t]; }
        atomicAdd(&msum[g * 32 + 2 * t], sx);
        atomicAdd(&msum[g * 32 + 2 * t + 1], sy);
    }
}

// pool with ctx recomputed per block. R28 parity split (g=bid&1): a3 reads
// hit the per-XCD L2 agg32 (same parity mapping) just wrote.
__global__ void pool2_kernel(const float* __restrict__ a3, const float* __restrict__ msum,
                             const float* __restrict__ W_att, float* __restrict__ pooled,
                             int N, int halfgrid) {
    int g = blockIdx.x & 1;
    int bid = blockIdx.x >> 1;
    int t = threadIdx.x;
    int j = t & 31;
    float invN = 1.f / (float)N;
    float acc = 0.f;
    for (int i = 0; i < 32; ++i) acc += (msum[g * 32 + i] * invN) * W_att[i * 32 + j];
    float cj = tanhf(acc);
    int hw = (bid * blockDim.x + t) >> 5;
    int nhw = (halfgrid * blockDim.x) >> 5;
    const float* base = a3 + (size_t)g * N * 32;
    float local = 0.f;
    for (int n = hw; n < N; n += nhw) {
        float v = base[(size_t)n * 32 + j];
        float d = v * cj;
        #pragma unroll
        for (int off = 16; off; off >>= 1) d += __shfl_xor(d, off);
        float s = 1.f / (1.f + __expf(-d));
        local += s * v;
    }
    __shared__ float sp[256];
    sp[t] = local;
    __syncthreads();
    if (t < 32) {
        float s = 0.f;
        for (int w = 0; w < 8; ++w) s += sp[w * 32 + t];
        atomicAdd(&pooled[g * 32 + t], s);
    }
}

__global__ void ntn_kernel(const float* __restrict__ p1, const float* __restrict__ p2,
                           const float* __restrict__ W_tn, const float* __restrict__ W_block,
                           const float* __restrict__ b_tn, float* __restrict__ out) {
    int k = threadIdx.x;
    if (k >= 16) return;
    float sc = 0.f;
    for (int i = 0; i < 32; ++i) {
        float e1 = p1[i];
        for (int j = 0; j < 32; ++j) sc += e1 * W_tn[i * 512 + j * 16 + k] * p2[j];
    }
    float bl = 0.f;
    for (int j = 0; j < 32; ++j)
        bl += W_block[k * 64 + j] * p1[j] + W_block[k * 64 + 32 + j] * p2[j];
    float v = sc + bl + b_tn[k];
    out[k] = v > 0.f ? v : 0.f;
}

extern "C" void kernel_launch(void* const* d_in, const int* in_sizes, int n_in,
                              void* d_out, int out_size, void* d_ws, size_t ws_size,
                              hipStream_t stream) {
    const float* f1     = (const float*)d_in[0];
    const int*   ei1    = (const int*)  d_in[1];
    const float* f2     = (const float*)d_in[2];
    const int*   ei2    = (const int*)  d_in[3];
    const float* W1     = (const float*)d_in[4];
    const float* b1     = (const float*)d_in[5];
    const float* W2     = (const float*)d_in[6];
    const float* b2     = (const float*)d_in[7];
    const float* W3     = (const float*)d_in[8];
    const float* b3     = (const float*)d_in[9];
    const float* W_att  = (const float*)d_in[10];
    const float* W_tn   = (const float*)d_in[11];
    const float* W_blk  = (const float*)d_in[12];
    const float* b_tn   = (const float*)d_in[13];

    int N = in_sizes[0] / 64;
    int E = in_sizes[1] / 2;
    int M = 2 * N;
    int E2 = 2 * E;
    int nsb = 9;
    while ((NSLICE << nsb) < M) nsb++;
    int cap = E2 / NSLICE + E2 / (4 * NSLICE) + 1024;   // avg + 25% + 1K slack

    char* ws = (char*)d_ws;
    size_t off = 0;
    auto alloc = [&](size_t bytes) -> void* {
        void* p = ws + off;
        off += (bytes + 511) & ~(size_t)511;
        return p;
    };
    _Float16*  xsA     = (_Float16*) alloc((size_t)M * 64 * sizeof(_Float16)); // xs0; h3s reuse
    _Float16*  xsB     = (_Float16*) alloc((size_t)M * 64 * sizeof(_Float16)); // xs1
    // a3 (f32, M*32) shares region with bkt (uint32, NSLICE*cap): bkt dies at fillC.
    size_t a3_bytes  = (size_t)M * 32 * sizeof(float);
    size_t bkt_bytes = (size_t)NSLICE * cap * sizeof(unsigned);
    char*  region    = (char*)alloc(a3_bytes > bkt_bytes ? a3_bytes : bkt_bytes);
    float*    a3  = (float*)region;
    unsigned* bkt = (unsigned*)region;
    int*       col     = (int*)      alloc((size_t)E2 * sizeof(int));
    int*       row_ptr = (int*)      alloc((size_t)(M + 1) * sizeof(int));
    float*     dinv    = (float*)    alloc((size_t)M * sizeof(float));
    int*       gslice  = (int*)      alloc(NSLICE * sizeof(int));
    _Float16*  pk      = (_Float16*) alloc(10240 * sizeof(_Float16));
    float*     smalls  = (float*)    alloc(256 * sizeof(float));
    float* msum   = smalls;
    float* pooled = smalls + 64;
    _Float16* pk1 = pk, *pk2 = pk + 4096, *pk3 = pk + 8192;

    hipMemsetAsync(smalls, 0, 256 * sizeof(float), stream);
    hipMemsetAsync(gslice, 0, NSLICE * sizeof(int), stream);

    int chunk = (E2 + NBLK - 1) / NBLK;
    int lds_fused = ((1 << nsb) + FILLC_T) * sizeof(int) + (1 << nsb) * sizeof(float);

    // CSR build (R30: packW folded into bucket; scale0 folded into fillC)
    bucket_fused_kernel<<<NBLK, 256, 0, stream>>>(ei1, ei2, E, N, gslice, bkt, chunk, nsb, cap,
                                                  W1, W2, W3, pk);
    fillC_fused_kernel<<<NSLICE, FILLC_T, lds_fused, stream>>>(bkt, gslice, row_ptr, dinv, col,
                                                               f1, f2, xsA, M, N, nsb, cap);

    // Fused GCN stack (R27): block = 16 nodes = one MFMA tile; parity kept.
    int nbg = 2 * ((N + 15) / 16);
    agg_gemm1_kernel<<<nbg, 256, 0, stream>>>(xsA, xsB, row_ptr, col, pk1, b1, dinv, N);      // xs1
    agg_gemm2_kernel<<<nbg, 256, 0, stream>>>(xsB, xsA, row_ptr, col, pk2, pk3, b2, dinv, N); // h3s

    const int HG = 512;   // SETTLED: R14 (thrash) + R20 (L2-fit) both regress at 1024
    agg32_colsum_kernel<<<2 * HG, 256, 0, stream>>>(xsA, a3, row_ptr, col, dinv, b3, msum, N, HG);

    pool2_kernel<<<2 * 256, 256, 0, stream>>>(a3, msum, W_att, pooled, N, 256);
    ntn_kernel<<<1, 64, 0, stream>>>(pooled, pooled + 32, W_tn, W_blk, b_tn, (float*)d_out);
}

// Round 19
// 300.444 us; speedup vs baseline: 1.0021x; 1.0021x over previous
//
#include <hip/hip_runtime.h>
#include <math.h>

// ---------------------------------------------------------------------------
// SimGNN forward on MI355X — R29-exact revert (299.7 us best).
// R30 post-mortem: scale0/packW fusion NEUTRAL-NEGATIVE (301.1): launch gaps
// are ~1 us on this harness, cheaper than the serialization added by folding
// scale0 behind fillC phase 3. Kernel-count reduction exhausted. REVERTED.
// Final structure ledger:
//  - 3 gather passes ~49-50 us each (~150 us): L2 request-rate bound,
//    probed immovable 5 ways (R20 waves^, R24 width v, R25 width ^,
//    R24 L2-fit, R17/R22 parity). CLOSED.
//  - CSR build ~15 us: single-pass chunk-reservation bucket (R28) +
//    full-chip fillC (R29, NSLICE=256).
//  - agg64+GEMM fused (R27); packed-bkt uint32 (R23); parity splits
//    agg32/agg64/pool2 (R17/R22/R28); HG=512 SETTLED (R14+R20).
//  - R26 last-block-flag banned (container failures).
// Pipeline: bucket_fused -> fillC_fused -> packW/scale0
//   -> agg_gemm1 -> agg_gemm2 -> agg32_colsum -> pool2 -> ntn
// ---------------------------------------------------------------------------

#define NSLICE 256
#define NBLK   256
#define FILLC_T 512

typedef _Float16 f16x8 __attribute__((ext_vector_type(8)));
typedef _Float16 f16x4 __attribute__((ext_vector_type(4)));
typedef _Float16 f16x2 __attribute__((ext_vector_type(2)));
typedef float    f32x4 __attribute__((ext_vector_type(4)));

// ---- R28/R29: single-pass bucket build. Pass 1: LDS per-slice counts of
// this block's chunk. Reserve: one global atomicAdd per (block,slice).
// Pass 2: re-read chunk (L2-hot), place packed words into slice-chunked bkt.
__global__ void bucket_fused_kernel(const int* __restrict__ ei1, const int* __restrict__ ei2,
                                    int E, int N, int* __restrict__ gslice,
                                    unsigned* __restrict__ bkt, int chunk, int nsb, int cap) {
    __shared__ int cnt[NSLICE];
    __shared__ int rbase[NSLICE];
    int t = threadIdx.x;                   // blockDim.x == 256 == NSLICE
    if (t < NSLICE) cnt[t] = 0;
    __syncthreads();
    int E2 = 2 * E;
    int lo = blockIdx.x * chunk;
    int hi = lo + chunk; if (hi > E2) hi = E2;
    for (int i = lo + t; i < hi; i += blockDim.x) {
        int dst = (i < E) ? ei1[E + i] : (ei2[E + (i - E)] + N);
        atomicAdd(&cnt[dst >> nsb], 1);
    }
    __syncthreads();
    if (t < NSLICE) {
        int c = cnt[t];
        rbase[t] = c ? atomicAdd(&gslice[t], c) : 0;
        cnt[t] = 0;                        // reuse as intra-block cursor
    }
    __syncthreads();
    unsigned mask = (1u << nsb) - 1u;
    for (int i = lo + t; i < hi; i += blockDim.x) {
        int src, dst;
        if (i < E) { src = ei1[i];         dst = ei1[E + i]; }
        else       { src = ei2[i - E] + N; dst = ei2[E + (i - E)] + N; }
        int s = dst >> nsb;
        int p = rbase[s] + atomicAdd(&cnt[s], 1);
        if (p >= cap) p = cap - 1;         // overflow clamp (no fault)
        bkt[(size_t)s * cap + p] = ((unsigned)src << nsb) | ((unsigned)dst & mask);
    }
}

// ---- fillC_fused (R29): 256 blocks x 512 threads. sliceStart from summing
// gslice. Phase 1 LDS histogram -> phase 2 scan (row_ptr/dinv) -> phase 3
// col placement. PER = nbins/512 (= 1 at nsb=9).
__global__ void fillC_fused_kernel(const unsigned* __restrict__ bkt,
                                   const int* __restrict__ gslice,
                                   int* __restrict__ row_ptr, float* __restrict__ dinv,
                                   int* __restrict__ col, int M, int nsb, int cap) {
    extern __shared__ int sm[];           // [nbins] hist/cursor + [512] scan
    int nbins = 1 << nsb;
    unsigned mask = (unsigned)nbins - 1u;
    int* hist = sm;
    int* ssum = sm + nbins;
    __shared__ int gs[NSLICE];
    int slice = blockIdx.x;
    int lo = slice << nsb;
    int t = threadIdx.x;                  // blockDim.x == FILLC_T
    for (int j = t; j < NSLICE; j += FILLC_T) gs[j] = gslice[j];
    for (int j = t; j < nbins; j += FILLC_T) hist[j] = 0;
    __syncthreads();
    int sstart = 0;
    for (int k = 0; k < slice; ++k) sstart += gs[k];
    int scount = gs[slice];
    size_t sb = (size_t)slice * cap;
    // Phase 1: histogram over low bits
    for (int i = t; i < scount; i += FILLC_T)
        atomicAdd(&hist[bkt[sb + i] & mask], 1);
    __syncthreads();
    // Phase 2: exclusive scan over nbins
    const int PER = nbins >> 9;           // nbins/512
    int base = t * PER;
    int vals[8];                          // supports nsb up to 12
    int acc = 0;
    for (int k = 0; k < PER; ++k) { vals[k] = hist[base + k]; acc += vals[k]; }
    ssum[t] = acc;
    __syncthreads();
    for (int off = 1; off < FILLC_T; off <<= 1) {
        int v = (t >= off) ? ssum[t - off] : 0;
        __syncthreads();
        ssum[t] += v;
        __syncthreads();
    }
    int run = sstart + ((t == 0) ? 0 : ssum[t - 1]);
    for (int k = 0; k < PER; ++k) {
        int idx = lo + base + k;
        if (idx < M) {
            row_ptr[idx] = run;
            dinv[idx] = rsqrtf((float)(vals[k] + 1));
        }
        hist[base + k] = run;             // becomes the global write cursor
        run += vals[k];
    }
    __syncthreads();
    if (slice == NSLICE - 1 && t == 0) row_ptr[M] = sstart + scount;  // = E2
    // Phase 3: place edges (src = high bits)
    for (int i = t; i < scount; i += FILLC_T) {
        unsigned w = bkt[sb + i];
        int p = atomicAdd(&hist[w & mask], 1);
        col[p] = (int)(w >> nsb);
    }
}

// xs0[i] = f16(x0[i] * dinv[i/64]); 4 elements per thread.
__global__ void scale0_kernel(const float* __restrict__ f1, const float* __restrict__ f2,
                              const float* __restrict__ dinv, _Float16* __restrict__ xs,
                              int n /* = N*64 */) {
    int i4 = (blockIdx.x * blockDim.x + threadIdx.x) * 4;
    if (i4 >= 2 * n) return;
    const float* src = (i4 < n) ? (f1 + i4) : (f2 + (i4 - n));
    float dv = dinv[i4 >> 6];
    float4 v = *(const float4*)src;
    f16x4 o = { (_Float16)(v.x * dv), (_Float16)(v.y * dv),
                (_Float16)(v.z * dv), (_Float16)(v.w * dv) };
    *(f16x4*)(xs + i4) = o;
}

// Pack W1,W2 (64x64) and W3 (64x32) into MFMA B-fragment order, f16.
__global__ void packW_kernel(const float* __restrict__ W1, const float* __restrict__ W2,
                             const float* __restrict__ W3, _Float16* __restrict__ pk) {
    int t = blockIdx.x * blockDim.x + threadIdx.x;
    if (t < 8192) {
        const float* W = (t < 4096) ? W1 : W2;
        int idx = t & 4095;
        int j = idx & 7, slot = idx >> 3;
        int lane = slot & 63, s = (slot >> 6) & 1, ct = slot >> 7;
        int k = s * 32 + ((lane >> 4) << 3) + j;
        int n = ct * 16 + (lane & 15);
        pk[t] = (_Float16)W[k * 64 + n];
    } else if (t < 10240) {
        int idx = t - 8192;
        int j = idx & 7, slot = idx >> 3;
        int lane = slot & 63, s = (slot >> 6) & 1, ct = slot >> 7;
        int k = s * 32 + ((lane >> 4) << 3) + j;
        int n = ct * 16 + (lane & 15);
        pk[t] = (_Float16)W3[k * 32 + n];
    }
}

// Gather one node's 64-f16 row (f16x4 lane slice), R25-exact loop.
__device__ inline void gather_row4(const _Float16* __restrict__ xs,
                                   const int* __restrict__ row_ptr,
                                   const int* __restrict__ col,
                                   int v, int l, float a[4]) {
    const f16x4* row = (const f16x4*)(xs + (size_t)v * 64);
    f16x4 sv = row[l];
    a[0] = (float)sv[0]; a[1] = (float)sv[1]; a[2] = (float)sv[2]; a[3] = (float)sv[3];
    int s = row_ptr[v], e = row_ptr[v + 1];
    int i = s;
    for (; i + 8 <= e; i += 8) {
        int u0 = col[i],     u1 = col[i + 1], u2 = col[i + 2], u3 = col[i + 3];
        int u4 = col[i + 4], u5 = col[i + 5], u6 = col[i + 6], u7 = col[i + 7];
        f16x4 p0 = ((const f16x4*)(xs + (size_t)u0 * 64))[l];
        f16x4 p1 = ((const f16x4*)(xs + (size_t)u1 * 64))[l];
        f16x4 p2 = ((const f16x4*)(xs + (size_t)u2 * 64))[l];
        f16x4 p3 = ((const f16x4*)(xs + (size_t)u3 * 64))[l];
        f16x4 p4 = ((const f16x4*)(xs + (size_t)u4 * 64))[l];
        f16x4 p5 = ((const f16x4*)(xs + (size_t)u5 * 64))[l];
        f16x4 p6 = ((const f16x4*)(xs + (size_t)u6 * 64))[l];
        f16x4 p7 = ((const f16x4*)(xs + (size_t)u7 * 64))[l];
        a[0] += (((float)p0[0] + (float)p1[0]) + ((float)p2[0] + (float)p3[0]))
              + (((float)p4[0] + (float)p5[0]) + ((float)p6[0] + (float)p7[0]));
        a[1] += (((float)p0[1] + (float)p1[1]) + ((float)p2[1] + (float)p3[1]))
              + (((float)p4[1] + (float)p5[1]) + ((float)p6[1] + (float)p7[1]));
        a[2] += (((float)p0[2] + (float)p1[2]) + ((float)p2[2] + (float)p3[2]))
              + (((float)p4[2] + (float)p5[2]) + ((float)p6[2] + (float)p7[2]));
        a[3] += (((float)p0[3] + (float)p1[3]) + ((float)p2[3] + (float)p3[3]))
              + (((float)p4[3] + (float)p5[3]) + ((float)p6[3] + (float)p7[3]));
    }
    for (; i + 4 <= e; i += 4) {
        int u0 = col[i], u1 = col[i + 1], u2 = col[i + 2], u3 = col[i + 3];
        f16x4 p0 = ((const f16x4*)(xs + (size_t)u0 * 64))[l];
        f16x4 p1 = ((const f16x4*)(xs + (size_t)u1 * 64))[l];
        f16x4 p2 = ((const f16x4*)(xs + (size_t)u2 * 64))[l];
        f16x4 p3 = ((const f16x4*)(xs + (size_t)u3 * 64))[l];
        a[0] += ((float)p0[0] + (float)p1[0]) + ((float)p2[0] + (float)p3[0]);
        a[1] += ((float)p0[1] + (float)p1[1]) + ((float)p2[1] + (float)p3[1]);
        a[2] += ((float)p0[2] + (float)p1[2]) + ((float)p2[2] + (float)p3[2]);
        a[3] += ((float)p0[3] + (float)p1[3]) + ((float)p2[3] + (float)p3[3]);
    }
    for (; i < e; ++i) {
        f16x4 p = ((const f16x4*)(xs + (size_t)col[i] * 64))[l];
        a[0] += (float)p[0]; a[1] += (float)p[1]; a[2] += (float)p[2]; a[3] += (float)p[3];
    }
}

// R27: fused agg64 + GEMM1. Block = 16 quarter-waves = 16 nodes = one MFMA
// tile. Gather -> LDS[16][72] -> 4 waves x 1 ct-tile. g=bid&1 parity kept.
__global__ void agg_gemm1_kernel(const _Float16* __restrict__ xs, _Float16* __restrict__ out,
                                 const int* __restrict__ row_ptr, const int* __restrict__ col,
                                 const _Float16* __restrict__ pk, const float* __restrict__ b1,
                                 const float* __restrict__ dinv, int N) {
    __shared__ _Float16 xl[16][72];
    int g = blockIdx.x & 1;
    int tile = blockIdx.x >> 1;
    int t = threadIdx.x;
    int qw = t >> 4, l = t & 15;
    int nv = tile * 16 + qw;
    int v0 = g * N + tile * 16;
    if (nv < N) {
        int v = g * N + nv;
        float a[4];
        gather_row4(xs, row_ptr, col, v, l, a);
        float dvv = dinv[v];
        f16x4 o = { (_Float16)(a[0] * dvv), (_Float16)(a[1] * dvv),
                    (_Float16)(a[2] * dvv), (_Float16)(a[3] * dvv) };
        *(f16x4*)&xl[qw][l * 4] = o;
    } else {
        f16x4 z = { (_Float16)0.f, (_Float16)0.f, (_Float16)0.f, (_Float16)0.f };
        *(f16x4*)&xl[qw][l * 4] = z;
    }
    __syncthreads();
    int ct = t >> 6;                       // wave id = column tile
    int lane = t & 63;
    int l15 = lane & 15, q = lane >> 4;
    const f16x8* arow = (const f16x8*)&xl[l15][0];
    f16x8 a0 = arow[q];
    f16x8 a1 = arow[q + 4];
    const f16x8* bp = (const f16x8*)pk;
    f32x4 c = {0.f, 0.f, 0.f, 0.f};
    c = __builtin_amdgcn_mfma_f32_16x16x32_f16(a0, bp[(ct * 2 + 0) * 64 + lane], c, 0, 0, 0);
    c = __builtin_amdgcn_mfma_f32_16x16x32_f16(a1, bp[(ct * 2 + 1) * 64 + lane], c, 0, 0, 0);
    float bj = b1[ct * 16 + l15];
    #pragma unroll
    for (int r = 0; r < 4; ++r) {
        int nr = tile * 16 + q * 4 + r;
        if (nr < N) {
            int vr = v0 + q * 4 + r;
            out[(size_t)vr * 64 + ct * 16 + l15] =
                (_Float16)(fmaxf(c[r] + bj, 0.f) * dinv[vr]);
        }
    }
}

// R27: fused agg64 + GEMM2+GEMM3. Gather -> LDS -> relu(t@W2+b2) -> LDS2
// -> (@W3)*dinv -> h3s.
__global__ void agg_gemm2_kernel(const _Float16* __restrict__ xs, _Float16* __restrict__ out,
                                 const int* __restrict__ row_ptr, const int* __restrict__ col,
                                 const _Float16* __restrict__ pk2, const _Float16* __restrict__ pk3,
                                 const float* __restrict__ b2, const float* __restrict__ dinv,
                                 int N) {
    __shared__ _Float16 xl[16][72];
    __shared__ _Float16 x2[16][72];
    int g = blockIdx.x & 1;
    int tile = blockIdx.x >> 1;
    int t = threadIdx.x;
    int qw = t >> 4, l = t & 15;
    int nv = tile * 16 + qw;
    int v0 = g * N + tile * 16;
    if (nv < N) {
        int v = g * N + nv;
        float a[4];
        gather_row4(xs, row_ptr, col, v, l, a);
        float dvv = dinv[v];
        f16x4 o = { (_Float16)(a[0] * dvv), (_Float16)(a[1] * dvv),
                    (_Float16)(a[2] * dvv), (_Float16)(a[3] * dvv) };
        *(f16x4*)&xl[qw][l * 4] = o;
    } else {
        f16x4 z = { (_Float16)0.f, (_Float16)0.f, (_Float16)0.f, (_Float16)0.f };
        *(f16x4*)&xl[qw][l * 4] = z;
    }
    __syncthreads();
    int ct = t >> 6;
    int lane = t & 63;
    int l15 = lane & 15, q = lane >> 4;
    {
        const f16x8* arow = (const f16x8*)&xl[l15][0];
        f16x8 a0 = arow[q];
        f16x8 a1 = arow[q + 4];
        const f16x8* bp2 = (const f16x8*)pk2;
        f32x4 c = {0.f, 0.f, 0.f, 0.f};
        c = __builtin_amdgcn_mfma_f32_16x16x32_f16(a0, bp2[(ct * 2 + 0) * 64 + lane], c, 0, 0, 0);
        c = __builtin_amdgcn_mfma_f32_16x16x32_f16(a1, bp2[(ct * 2 + 1) * 64 + lane], c, 0, 0, 0);
        float bj = b2[ct * 16 + l15];
        #pragma unroll
        for (int r = 0; r < 4; ++r)
            x2[q * 4 + r][ct * 16 + l15] = (_Float16)fmaxf(c[r] + bj, 0.f);
    }
    __syncthreads();
    if (ct < 2) {
        const f16x8* er = (const f16x8*)&x2[l15][0];
        f16x8 e0 = er[q];
        f16x8 e1 = er[q + 4];
        const f16x8* bp3 = (const f16x8*)pk3;
        f32x4 c = {0.f, 0.f, 0.f, 0.f};
        c = __builtin_amdgcn_mfma_f32_16x16x32_f16(e0, bp3[(ct * 2 + 0) * 64 + lane], c, 0, 0, 0);
        c = __builtin_amdgcn_mfma_f32_16x16x32_f16(e1, bp3[(ct * 2 + 1) * 64 + lane], c, 0, 0, 0);
        #pragma unroll
        for (int r = 0; r < 4; ++r) {
            int nr = tile * 16 + q * 4 + r;
            if (nr < N) {
                int vr = v0 + q * 4 + r;
                out[(size_t)vr * 32 + ct * 16 + l15] = (_Float16)(c[r] * dinv[vr]);
            }
        }
    }
}

// agg32: quarter-wave per node; a3 f32 out; fused colsums.
// R17 parity split; HG=512 SETTLED (R14+R20: L2 queue-bound).
__global__ void agg32_colsum_kernel(const _Float16* __restrict__ hs, float* __restrict__ out,
                                    const int* __restrict__ row_ptr, const int* __restrict__ col,
                                    const float* __restrict__ dinv, const float* __restrict__ b,
                                    float* __restrict__ msum, int N, int halfgrid) {
    int g = blockIdx.x & 1;
    int bid = blockIdx.x >> 1;
    int t = threadIdx.x;
    int l = t & 15;
    int qw = (bid * blockDim.x + t) >> 4;
    int nqw = (halfgrid * blockDim.x) >> 4;
    float blx = b[2 * l], bly = b[2 * l + 1];
    float csx = 0.f, csy = 0.f;
    int base = g * N;
    for (int vv = qw; vv < N; vv += nqw) {
        int v = base + vv;
        f16x2 sv = ((const f16x2*)(hs + (size_t)v * 32))[l];
        float ax = (float)sv.x, ay = (float)sv.y;
        int s = row_ptr[v], e = row_ptr[v + 1];
        int i = s;
        for (; i + 8 <= e; i += 8) {
            int u0 = col[i],     u1 = col[i + 1], u2 = col[i + 2], u3 = col[i + 3];
            int u4 = col[i + 4], u5 = col[i + 5], u6 = col[i + 6], u7 = col[i + 7];
            f16x2 p0 = ((const f16x2*)(hs + (size_t)u0 * 32))[l];
            f16x2 p1 = ((const f16x2*)(hs + (size_t)u1 * 32))[l];
            f16x2 p2 = ((const f16x2*)(hs + (size_t)u2 * 32))[l];
            f16x2 p3 = ((const f16x2*)(hs + (size_t)u3 * 32))[l];
            f16x2 p4 = ((const f16x2*)(hs + (size_t)u4 * 32))[l];
            f16x2 p5 = ((const f16x2*)(hs + (size_t)u5 * 32))[l];
            f16x2 p6 = ((const f16x2*)(hs + (size_t)u6 * 32))[l];
            f16x2 p7 = ((const f16x2*)(hs + (size_t)u7 * 32))[l];
            ax += (((float)p0.x + (float)p1.x) + ((float)p2.x + (float)p3.x))
                + (((float)p4.x + (float)p5.x) + ((float)p6.x + (float)p7.x));
            ay += (((float)p0.y + (float)p1.y) + ((float)p2.y + (float)p3.y))
                + (((float)p4.y + (float)p5.y) + ((float)p6.y + (float)p7.y));
        }
        for (; i + 4 <= e; i += 4) {
            int u0 = col[i], u1 = col[i + 1], u2 = col[i + 2], u3 = col[i + 3];
            f16x2 p0 = ((const f16x2*)(hs + (size_t)u0 * 32))[l];
            f16x2 p1 = ((const f16x2*)(hs + (size_t)u1 * 32))[l];
            f16x2 p2 = ((const f16x2*)(hs + (size_t)u2 * 32))[l];
            f16x2 p3 = ((const f16x2*)(hs + (size_t)u3 * 32))[l];
            ax += ((float)p0.x + (float)p1.x) + ((float)p2.x + (float)p3.x);
            ay += ((float)p0.y + (float)p1.y) + ((float)p2.y + (float)p3.y);
        }
        for (; i < e; ++i) {
            f16x2 p = ((const f16x2*)(hs + (size_t)col[i] * 32))[l];
            ax += (float)p.x; ay += (float)p.y;
        }
        float dv = dinv[v];
        float ox = ax * dv + blx, oy = ay * dv + bly;
        *(float2*)(out + (size_t)v * 32 + 2 * l) = make_float2(ox, oy);
        csx += ox; csy += oy;
    }
    __shared__ float spx[256], spy[256];
    spx[t] = csx; spy[t] = csy;
    __syncthreads();
    if (t < 16) {
        float sx = 0.f, sy = 0.f;
        for (int w = 0; w < 16; ++w) { sx += spx[w * 16 + t]; sy += spy[w * 16 + t]; }
        atomicAdd(&msum[g * 32 + 2 * t], sx);
        atomicAdd(&msum[g * 32 + 2 * t + 1], sy);
    }
}

// pool with ctx recomputed per block. R28 parity split (g=bid&1): a3 reads
// hit the per-XCD L2 agg32 (same parity mapping) just wrote.
__global__ void pool2_kernel(const float* __restrict__ a3, const float* __restrict__ msum,
                             const float* __restrict__ W_att, float* __restrict__ pooled,
                             int N, int halfgrid) {
    int g = blockIdx.x & 1;
    int bid = blockIdx.x >> 1;
    int t = threadIdx.x;
    int j = t & 31;
    float invN = 1.f / (float)N;
    float acc = 0.f;
    for (int i = 0; i < 32; ++i) acc += (msum[g * 32 + i] * invN) * W_att[i * 32 + j];
    float cj = tanhf(acc);
    int hw = (bid * blockDim.x + t) >> 5;
    int nhw = (halfgrid * blockDim.x) >> 5;
    const float* base = a3 + (size_t)g * N * 32;
    float local = 0.f;
    for (int n = hw; n < N; n += nhw) {
        float v = base[(size_t)n * 32 + j];
        float d = v * cj;
        #pragma unroll
        for (int off = 16; off; off >>= 1) d += __shfl_xor(d, off);
        float s = 1.f / (1.f + __expf(-d));
        local += s * v;
    }
    __shared__ float sp[256];
    sp[t] = local;
    __syncthreads();
    if (t < 32) {
        float s = 0.f;
        for (int w = 0; w < 8; ++w) s += sp[w * 32 + t];
        atomicAdd(&pooled[g * 32 + t], s);
    }
}

__global__ void ntn_kernel(const float* __restrict__ p1, const float* __restrict__ p2,
                           const float* __restrict__ W_tn, const float* __restrict__ W_block,
                           const float* __restrict__ b_tn, float* __restrict__ out) {
    int k = threadIdx.x;
    if (k >= 16) return;
    float sc = 0.f;
    for (int i = 0; i < 32; ++i) {
        float e1 = p1[i];
        for (int j = 0; j < 32; ++j) sc += e1 * W_tn[i * 512 + j * 16 + k] * p2[j];
    }
    float bl = 0.f;
    for (int j = 0; j < 32; ++j)
        bl += W_block[k * 64 + j] * p1[j] + W_block[k * 64 + 32 + j] * p2[j];
    float v = sc + bl + b_tn[k];
    out[k] = v > 0.f ? v : 0.f;
}

extern "C" void kernel_launch(void* const* d_in, const int* in_sizes, int n_in,
                              void* d_out, int out_size, void* d_ws, size_t ws_size,
                              hipStream_t stream) {
    const float* f1     = (const float*)d_in[0];
    const int*   ei1    = (const int*)  d_in[1];
    const float* f2     = (const float*)d_in[2];
    const int*   ei2    = (const int*)  d_in[3];
    const float* W1     = (const float*)d_in[4];
    const float* b1     = (const float*)d_in[5];
    const float* W2     = (const float*)d_in[6];
    const float* b2     = (const float*)d_in[7];
    const float* W3     = (const float*)d_in[8];
    const float* b3     = (const float*)d_in[9];
    const float* W_att  = (const float*)d_in[10];
    const float* W_tn   = (const float*)d_in[11];
    const float* W_blk  = (const float*)d_in[12];
    const float* b_tn   = (const float*)d_in[13];

    int N = in_sizes[0] / 64;
    int E = in_sizes[1] / 2;
    int M = 2 * N;
    int E2 = 2 * E;
    int nsb = 9;
    while ((NSLICE << nsb) < M) nsb++;
    int cap = E2 / NSLICE + E2 / (4 * NSLICE) + 1024;   // avg + 25% + 1K slack

    char* ws = (char*)d_ws;
    size_t off = 0;
    auto alloc = [&](size_t bytes) -> void* {
        void* p = ws + off;
        off += (bytes + 511) & ~(size_t)511;
        return p;
    };
    _Float16*  xsA     = (_Float16*) alloc((size_t)M * 64 * sizeof(_Float16)); // xs0; h3s reuse
    _Float16*  xsB     = (_Float16*) alloc((size_t)M * 64 * sizeof(_Float16)); // xs1
    // a3 (f32, M*32) shares region with bkt (uint32, NSLICE*cap): bkt dies at fillC.
    size_t a3_bytes  = (size_t)M * 32 * sizeof(float);
    size_t bkt_bytes = (size_t)NSLICE * cap * sizeof(unsigned);
    char*  region    = (char*)alloc(a3_bytes > bkt_bytes ? a3_bytes : bkt_bytes);
    float*    a3  = (float*)region;
    unsigned* bkt = (unsigned*)region;
    int*       col     = (int*)      alloc((size_t)E2 * sizeof(int));
    int*       row_ptr = (int*)      alloc((size_t)(M + 1) * sizeof(int));
    float*     dinv    = (float*)    alloc((size_t)M * sizeof(float));
    int*       gslice  = (int*)      alloc(NSLICE * sizeof(int));
    _Float16*  pk      = (_Float16*) alloc(10240 * sizeof(_Float16));
    float*     smalls  = (float*)    alloc(256 * sizeof(float));
    float* msum   = smalls;
    float* pooled = smalls + 64;
    _Float16* pk1 = pk, *pk2 = pk + 4096, *pk3 = pk + 8192;

    hipMemsetAsync(smalls, 0, 256 * sizeof(float), stream);
    hipMemsetAsync(gslice, 0, NSLICE * sizeof(int), stream);

    int chunk = (E2 + NBLK - 1) / NBLK;
    int lds_fused = ((1 << nsb) + FILLC_T) * sizeof(int);

    // CSR build (R29: 256 slices — fillC at full-chip occupancy)
    bucket_fused_kernel<<<NBLK, 256, 0, stream>>>(ei1, ei2, E, N, gslice, bkt, chunk, nsb, cap);
    fillC_fused_kernel<<<NSLICE, FILLC_T, lds_fused, stream>>>(bkt, gslice, row_ptr, dinv, col, M, nsb, cap);

    // Weight packing + pre-scaled f16 input table
    packW_kernel<<<40, 256, 0, stream>>>(W1, W2, W3, pk);
    int cvb = (M * 64 / 4 + 255) / 256;
    scale0_kernel<<<cvb, 256, 0, stream>>>(f1, f2, dinv, xsA, N * 64);

    // Fused GCN stack (R27): block = 16 nodes = one MFMA tile; parity kept.
    int nbg = 2 * ((N + 15) / 16);
    agg_gemm1_kernel<<<nbg, 256, 0, stream>>>(xsA, xsB, row_ptr, col, pk1, b1, dinv, N);      // xs1
    agg_gemm2_kernel<<<nbg, 256, 0, stream>>>(xsB, xsA, row_ptr, col, pk2, pk3, b2, dinv, N); // h3s

    const int HG = 512;   // SETTLED: R14 (thrash) + R20 (L2-fit) both regress at 1024
    agg32_colsum_kernel<<<2 * HG, 256, 0, stream>>>(xsA, a3, row_ptr, col, dinv, b3, msum, N, HG);

    pool2_kernel<<<2 * 256, 256, 0, stream>>>(a3, msum, W_att, pooled, N, 256);
    ntn_kernel<<<1, 64, 0, stream>>>(pooled, pooled + 32, W_tn, W_blk, b_tn, (float*)d_out);
}